// Round 7
// baseline (799.294 us; speedup 1.0000x reference)
//
#include <hip/hip_runtime.h>
#include <math.h>

#define AT 1024
#define NBR 32
#define FN 128
#define FE 128
#define ZIN 384
#define NA 4096              // B*At
#define NEDGE (NA * NBR)     // 131072
#define WSTRIDE (ZIN * FN)   // 49152 floats per layer
#define G_ENDF 5.5f
#define WTMAT (384 * 128)    // converted matrix elements (transposed [n][k])
#define EPART (256 * 128)    // offset of e-part rows within converted matrix

typedef unsigned short ushort_t;
typedef __attribute__((ext_vector_type(8))) short bf16x8;
typedef __attribute__((ext_vector_type(4))) float f32x4;

#define LOG2E 1.4426950408889634f
#define LN2   0.6931471805599453f

__device__ __forceinline__ float fexp(float x) {
    return __builtin_amdgcn_exp2f(x * LOG2E);
}
__device__ __forceinline__ float sigmoid_f(float x) {
    return __builtin_amdgcn_rcpf(1.0f + __builtin_amdgcn_exp2f(-x * LOG2E));
}
__device__ __forceinline__ float softplus_f(float x) {
    float t = __builtin_amdgcn_exp2f(-fabsf(x) * LOG2E);
    return fmaxf(x, 0.0f) + LN2 * __builtin_amdgcn_logf(1.0f + t);
}

__device__ __forceinline__ ushort_t f2bf(float f) {
    unsigned int u = __float_as_uint(f);
    u = (u + 0x7FFFu + ((u >> 16) & 1u)) >> 16;   // RTNE
    return (ushort_t)u;
}
__device__ __forceinline__ float bf2f(ushort_t h) {
    return __uint_as_float(((unsigned int)h) << 16);
}
__device__ __forceinline__ unsigned int cvt_pk_bf16(float a, float b) {
    unsigned int r;
    asm("v_cvt_pk_bf16_f32 %0, %1, %2" : "=v"(r) : "v"(a), "v"(b));
    return r;
}
__device__ __forceinline__ void split2(float a, float b,
                                       unsigned int& hi, unsigned int& lo) {
    hi = cvt_pk_bf16(a, b);
    float ha = __uint_as_float(hi << 16);
    float hb = __uint_as_float(hi & 0xffff0000u);
    lo = cvt_pk_bf16(a - ha, b - hb);
}

// -------- h0[atom][f] = emb[Z[atom]][f] --------
__global__ __launch_bounds__(256) void k_init_h(const int* __restrict__ Z,
                                                const float* __restrict__ emb,
                                                float* __restrict__ h) {
    int idx = blockIdx.x * 256 + threadIdx.x;
    int atom = idx >> 7, f = idx & 127;
    h[idx] = emb[Z[atom] * FN + f];
}

// -------- convert all 12 weight matrices to split-bf16, transposed [n][k] --------
__global__ __launch_bounds__(256) void k_conv_w(const float* __restrict__ Wnf,
                                                const float* __restrict__ Wnc,
                                                const float* __restrict__ Wef,
                                                const float* __restrict__ Wec,
                                                ushort_t* __restrict__ Whi,
                                                ushort_t* __restrict__ Wlo) {
    const int blk = blockIdx.x;         // 0..35
    const int w = blk / 3, p = blk % 3;
    const int l = w >> 2, t = w & 3;
    const float* src = (t == 0 ? Wnf : t == 1 ? Wnc : t == 2 ? Wef : Wec)
                       + (size_t)l * WSTRIDE + (size_t)p * 128 * 128;
    __shared__ float tile[128][129];
    const int tid = threadIdx.x;
    {
        int k = tid >> 1, h = (tid & 1) * 64;
#pragma unroll
        for (int i = 0; i < 16; ++i) {
            float4 v = *(const float4*)&src[k * 128 + h + i * 4];
            tile[k][h + i * 4 + 0] = v.x; tile[k][h + i * 4 + 1] = v.y;
            tile[k][h + i * 4 + 2] = v.z; tile[k][h + i * 4 + 3] = v.w;
        }
    }
    __syncthreads();
    {
        int f = tid >> 1, kh = (tid & 1) * 64;
        size_t orow = (size_t)(w * 384 + p * 128 + f) * 128;
#pragma unroll
        for (int i = 0; i < 64; i += 4) {
            ushort4 ph, pl;
            float x0 = tile[kh + i + 0][f]; ph.x = f2bf(x0); pl.x = f2bf(x0 - bf2f(ph.x));
            float x1 = tile[kh + i + 1][f]; ph.y = f2bf(x1); pl.y = f2bf(x1 - bf2f(ph.y));
            float x2 = tile[kh + i + 2][f]; ph.z = f2bf(x2); pl.z = f2bf(x2 - bf2f(ph.z));
            float x3 = tile[kh + i + 3][f]; ph.w = f2bf(x3); pl.w = f2bf(x3 - bf2f(ph.w));
            *(ushort4*)&Whi[orow + kh + i] = ph;
            *(ushort4*)&Wlo[orow + kh + i] = pl;
        }
    }
}

// -------- Wo1 [128][64] -> Wo1t [64 n][128 k] split bf16 --------
__global__ __launch_bounds__(256) void k_conv_wo(const float* __restrict__ Wo1,
                                                 ushort_t* __restrict__ Wh,
                                                 ushort_t* __restrict__ Wl) {
    int idx = blockIdx.x * 256 + threadIdx.x;  // over 8192
    int n = idx >> 7, k = idx & 127;
    float x = Wo1[k * 64 + n];
    ushort_t h = f2bf(x);
    Wh[idx] = h;
    Wl[idx] = f2bf(x - bf2f(h));
}

// -------- MFMA projection -> interleaved Pi/Pj: [atom][col][{f,c}] --------
__global__ __launch_bounds__(512, 4) void k_proj(
    const float* __restrict__ h,
    const ushort_t* __restrict__ Wah, const ushort_t* __restrict__ Wal,
    const ushort_t* __restrict__ Wbh, const ushort_t* __restrict__ Wbl,
    const float* __restrict__ ba, const float* __restrict__ bb,
    float* __restrict__ Pi, float* __restrict__ Pj) {
    const int tid = threadIdx.x;
    const int a0 = blockIdx.x * 16;
    __shared__ __align__(16) ushort_t sAh[16 * 136];
    __shared__ __align__(16) ushort_t sAl[16 * 136];
    {
        int row = tid >> 5, kq = (tid & 31) * 4;
        float4 v = *(const float4*)&h[(size_t)(a0 + row) * 128 + kq];
        unsigned int h0, l0, h1, l1;
        split2(v.x, v.y, h0, l0);
        split2(v.z, v.w, h1, l1);
        *(uint2*)&sAh[row * 136 + kq] = make_uint2(h0, h1);
        *(uint2*)&sAl[row * 136 + kq] = make_uint2(l0, l1);
    }
    __syncthreads();

    const int w = tid >> 6;
    const int lane = tid & 63;
    const int lrow = lane & 15;
    const int kgrp = (lane >> 4) * 8;

    f32x4 acc[4] = {};
#pragma unroll
    for (int kk = 0; kk < 4; ++kk) {
        const int kbase = kk * 32 + kgrp;
        bf16x8 ah = *(const bf16x8*)&sAh[lrow * 136 + kbase];
        bf16x8 al = *(const bf16x8*)&sAl[lrow * 136 + kbase];
#pragma unroll
        for (int nt = 0; nt < 4; ++nt) {
            int r512 = w * 64 + nt * 16 + lrow;
            const ushort_t* bh_p = (r512 < 256) ? (Wah + (size_t)r512 * 128)
                                                : (Wbh + (size_t)(r512 - 256) * 128);
            const ushort_t* bl_p = (r512 < 256) ? (Wal + (size_t)r512 * 128)
                                                : (Wbl + (size_t)(r512 - 256) * 128);
            bf16x8 bh = *(const bf16x8*)&bh_p[kbase];
            bf16x8 bl = *(const bf16x8*)&bl_p[kbase];
            acc[nt] = __builtin_amdgcn_mfma_f32_16x16x32_bf16(ah, bh, acc[nt], 0, 0, 0);
            acc[nt] = __builtin_amdgcn_mfma_f32_16x16x32_bf16(ah, bl, acc[nt], 0, 0, 0);
            acc[nt] = __builtin_amdgcn_mfma_f32_16x16x32_bf16(al, bh, acc[nt], 0, 0, 0);
        }
    }

    const int arr = w >> 1;
    float* dst = (arr & 1) ? Pj : Pi;
    const int slot = arr >> 1;
    const int rb = (lane >> 4) * 4;
#pragma unroll
    for (int nt = 0; nt < 4; ++nt) {
        int f = (w & 1) * 64 + nt * 16 + lrow;
        float bs = (arr == 0) ? ba[f] : (arr == 2) ? bb[f] : 0.0f;
#pragma unroll
        for (int r = 0; r < 4; ++r) {
            int row = rb + r;
            dst[((size_t)(a0 + row) * 128 + f) * 2 + slot] = acc[nt][r] + bs;
        }
    }
}

// -------- pipelined split-bf16 MFMA pass --------
// grid = NA/8 = 512 blocks (2/CU, whole grid resident); block = 4 tiles x 2 atoms.
// Double-buffered LDS; tile t+1's e+nbr loads issued before tile t's MFMA.
template <int NODE, int FIRST, int FUSE>
__global__ __launch_bounds__(512, 4) void k_pass(
    const float* __restrict__ e_g, float* __restrict__ e_out,
    const float* __restrict__ dist, const int* __restrict__ nbr_g,
    const float* __restrict__ Pi, const float* __restrict__ Pj,
    const ushort_t* __restrict__ Wfh, const ushort_t* __restrict__ Wfl,
    const ushort_t* __restrict__ Wch, const ushort_t* __restrict__ Wcl,
    const float* __restrict__ h_old, float* __restrict__ h_new,
    const ushort_t* __restrict__ Wo1h, const ushort_t* __restrict__ Wo1l,
    const float* __restrict__ bo1, const float* __restrict__ Wo2,
    const float* __restrict__ bo2, const float* __restrict__ unit,
    float* __restrict__ out) {
    const int tid = threadIdx.x;
    const int ab = blockIdx.x * 8;            // first atom of block (8 atoms total)
    const int base = (ab >> 10) << 10;        // batch base (8 | 1024 so uniform)

    __shared__ __align__(16) ushort_t sAh[2][64 * 136];
    __shared__ __align__(16) ushort_t sAl[2][64 * 136];
    __shared__ float sred[4][64];

    const int w = tid >> 6;
    const int lane = tid & 63;
    const int wr = w >> 2;        // 0..1 : 32-row group = one atom
    const int wc = w & 3;         // 0..3 : 32-col group
    const int lrow = lane & 15;
    const int kgrp = (lane >> 4) * 8;
    const int rb = (lane >> 4) * 4;
    const int srow = tid >> 3;            // staging: row 0..63
    const int skq = (tid & 7) * 16;       // staging: 16-col chunk

    const float delta = G_ENDF / 127.0f;
    const float coeff = -0.5f / (delta * delta);

    float ev[16];
    float dNext = 0.0f;
    int nbrNext[8];
    int nbrCur[8];

    // ---- prologue: load + stage tile 0 ----
    {
        const int a0 = ab;
        if (FIRST) {
            dNext = dist[a0 * 32 + srow];
        } else {
            size_t eoff = ((size_t)(a0 * 32 + srow)) * 128 + skq;
#pragma unroll
            for (int i = 0; i < 4; ++i) *(float4*)&ev[i * 4] = *(const float4*)&e_g[eoff + i * 4];
        }
#pragma unroll
        for (int i = 0; i < 8; ++i)
            nbrNext[i] = nbr_g[(a0 + wr) * 32 + (i >> 2) * 16 + rb + (i & 3)];
        if (FIRST) {
#pragma unroll
            for (int i = 0; i < 16; ++i) {
                float x = dNext - (float)(skq + i) * delta;
                ev[i] = fexp(coeff * x * x);
            }
            size_t eoff = ((size_t)(a0 * 32 + srow)) * 128 + skq;
#pragma unroll
            for (int i = 0; i < 4; ++i)
                *(float4*)&e_out[eoff + i * 4] =
                    make_float4(ev[i * 4], ev[i * 4 + 1], ev[i * 4 + 2], ev[i * 4 + 3]);
        }
#pragma unroll
        for (int i = 0; i < 4; ++i) {
            unsigned int h0, l0, h1, l1;
            split2(ev[i * 4 + 0], ev[i * 4 + 1], h0, l0);
            split2(ev[i * 4 + 2], ev[i * 4 + 3], h1, l1);
            *(uint2*)&sAh[0][srow * 136 + skq + i * 4] = make_uint2(h0, h1);
            *(uint2*)&sAl[0][srow * 136 + skq + i * 4] = make_uint2(l0, l1);
        }
#pragma unroll
        for (int i = 0; i < 8; ++i) nbrCur[i] = nbrNext[i];
    }
    __syncthreads();

#pragma unroll
    for (int t = 0; t < 4; ++t) {
        const int cur = t & 1;
        const int a0 = ab + t * 2;

        // ---- A: issue next-tile loads (pinned before MFMA) ----
        if (t < 3) {
            const int a1 = a0 + 2;
            if (FIRST) {
                dNext = dist[a1 * 32 + srow];
            } else {
                size_t eoff = ((size_t)(a1 * 32 + srow)) * 128 + skq;
#pragma unroll
                for (int i = 0; i < 4; ++i) *(float4*)&ev[i * 4] = *(const float4*)&e_g[eoff + i * 4];
            }
#pragma unroll
            for (int i = 0; i < 8; ++i)
                nbrNext[i] = nbr_g[(a1 + wr) * 32 + (i >> 2) * 16 + rb + (i & 3)];
        }
        __builtin_amdgcn_sched_barrier(0);

        // ---- B: MFMA on buf[cur] ----
        f32x4 accf[2][2] = {};
        f32x4 accc[2][2] = {};
#pragma unroll
        for (int kk = 0; kk < 4; ++kk) {
            const int kbase = kk * 32 + kgrp;
            bf16x8 ah[2], al[2];
#pragma unroll
            for (int mt = 0; mt < 2; ++mt) {
                ah[mt] = *(const bf16x8*)&sAh[cur][(wr * 32 + mt * 16 + lrow) * 136 + kbase];
                al[mt] = *(const bf16x8*)&sAl[cur][(wr * 32 + mt * 16 + lrow) * 136 + kbase];
            }
#pragma unroll
            for (int nt = 0; nt < 2; ++nt) {
                const int nn = wc * 32 + nt * 16 + lrow;
                bf16x8 bfh = *(const bf16x8*)&Wfh[(size_t)nn * 128 + kbase];
                bf16x8 bfl = *(const bf16x8*)&Wfl[(size_t)nn * 128 + kbase];
                bf16x8 bch = *(const bf16x8*)&Wch[(size_t)nn * 128 + kbase];
                bf16x8 bcl = *(const bf16x8*)&Wcl[(size_t)nn * 128 + kbase];
#pragma unroll
                for (int mt = 0; mt < 2; ++mt) {
                    accf[mt][nt] = __builtin_amdgcn_mfma_f32_16x16x32_bf16(ah[mt], bfh, accf[mt][nt], 0, 0, 0);
                    accf[mt][nt] = __builtin_amdgcn_mfma_f32_16x16x32_bf16(ah[mt], bfl, accf[mt][nt], 0, 0, 0);
                    accf[mt][nt] = __builtin_amdgcn_mfma_f32_16x16x32_bf16(al[mt], bfh, accf[mt][nt], 0, 0, 0);
                    accc[mt][nt] = __builtin_amdgcn_mfma_f32_16x16x32_bf16(ah[mt], bch, accc[mt][nt], 0, 0, 0);
                    accc[mt][nt] = __builtin_amdgcn_mfma_f32_16x16x32_bf16(ah[mt], bcl, accc[mt][nt], 0, 0, 0);
                    accc[mt][nt] = __builtin_amdgcn_mfma_f32_16x16x32_bf16(al[mt], bch, accc[mt][nt], 0, 0, 0);
                }
            }
        }

        if (FUSE) __syncthreads();   // all waves done reading buf[cur] before epilogue writes it

        // ---- C: epilogue ----
        float hsum[2] = {0.0f, 0.0f};
#pragma unroll
        for (int nt = 0; nt < 2; ++nt) {
            const int nn = wc * 32 + nt * 16 + lrow;
            const float2 piv = *(const float2*)&Pi[((size_t)(a0 + wr) * 128 + nn) * 2];
#pragma unroll
            for (int mt = 0; mt < 2; ++mt) {
#pragma unroll
                for (int r = 0; r < 4; ++r) {
                    const int rl = wr * 32 + mt * 16 + rb + r;
                    const int j = base + nbrCur[mt * 4 + r];
                    const float2 pjv = *(const float2*)&Pj[((size_t)j * 128 + nn) * 2];
                    float cf = accf[mt][nt][r] + piv.x + pjv.x;
                    float cc = accc[mt][nt][r] + piv.y + pjv.y;
                    float msg = sigmoid_f(cf) * softplus_f(cc);
                    if (NODE) {
                        hsum[nt] += msg;
                    } else {
                        const int lidx = rl * 136 + nn;
                        float eold = bf2f(sAh[cur][lidx]) + bf2f(sAl[cur][lidx]);
                        float enew = eold + msg;
                        if (FUSE) {
                            ushort_t hh = f2bf(enew);
                            sAh[cur][lidx] = hh;
                            sAl[cur][lidx] = f2bf(enew - bf2f(hh));
                        } else {
                            e_out[((size_t)(a0 * 32 + rl)) * 128 + nn] = enew;
                        }
                    }
                }
            }
        }

        if (NODE) {
#pragma unroll
            for (int nt = 0; nt < 2; ++nt) {
                float v = hsum[nt];
                v += __shfl_xor(v, 16, 64);
                v += __shfl_xor(v, 32, 64);
                if (lane < 16) {
                    int col = wc * 32 + nt * 16 + lane;
                    h_new[(size_t)(a0 + wr) * 128 + col] =
                        h_old[(size_t)(a0 + wr) * 128 + col] + v;
                }
            }
        }

        // ---- D: write next tile stage into buf[cur^1] ----
        if (t < 3) {
            if (FIRST) {
#pragma unroll
                for (int i = 0; i < 16; ++i) {
                    float x = dNext - (float)(skq + i) * delta;
                    ev[i] = fexp(coeff * x * x);
                }
                size_t eoff = ((size_t)((a0 + 2) * 32 + srow)) * 128 + skq;
#pragma unroll
                for (int i = 0; i < 4; ++i)
                    *(float4*)&e_out[eoff + i * 4] =
                        make_float4(ev[i * 4], ev[i * 4 + 1], ev[i * 4 + 2], ev[i * 4 + 3]);
            }
#pragma unroll
            for (int i = 0; i < 4; ++i) {
                unsigned int h0, l0, h1, l1;
                split2(ev[i * 4 + 0], ev[i * 4 + 1], h0, l0);
                split2(ev[i * 4 + 2], ev[i * 4 + 3], h1, l1);
                *(uint2*)&sAh[cur ^ 1][srow * 136 + skq + i * 4] = make_uint2(h0, h1);
                *(uint2*)&sAl[cur ^ 1][srow * 136 + skq + i * 4] = make_uint2(l0, l1);
            }
#pragma unroll
            for (int i = 0; i < 8; ++i) nbrCur[i] = nbrNext[i];
        }
        __syncthreads();

        // ---- FUSE: output head on e_new (in buf[cur]) ----
        if (FUSE) {
            f32x4 acco[2] = {};
            const int col = wc * 16 + lrow;
#pragma unroll
            for (int kk = 0; kk < 4; ++kk) {
                const int kbase = kk * 32 + kgrp;
                bf16x8 bh = *(const bf16x8*)&Wo1h[(size_t)col * 128 + kbase];
                bf16x8 bl = *(const bf16x8*)&Wo1l[(size_t)col * 128 + kbase];
#pragma unroll
                for (int mt = 0; mt < 2; ++mt) {
                    bf16x8 ah = *(const bf16x8*)&sAh[cur][(wr * 32 + mt * 16 + lrow) * 136 + kbase];
                    bf16x8 al = *(const bf16x8*)&sAl[cur][(wr * 32 + mt * 16 + lrow) * 136 + kbase];
                    acco[mt] = __builtin_amdgcn_mfma_f32_16x16x32_bf16(ah, bh, acco[mt], 0, 0, 0);
                    acco[mt] = __builtin_amdgcn_mfma_f32_16x16x32_bf16(ah, bl, acco[mt], 0, 0, 0);
                    acco[mt] = __builtin_amdgcn_mfma_f32_16x16x32_bf16(al, bh, acco[mt], 0, 0, 0);
                }
            }
            const float b1 = bo1[col];
            const float w2 = Wo2[col];
#pragma unroll
            for (int mt = 0; mt < 2; ++mt) {
#pragma unroll
                for (int r = 0; r < 4; ++r) {
                    float val = softplus_f(acco[mt][r] + b1) * w2;
                    val += __shfl_xor(val, 1, 64);
                    val += __shfl_xor(val, 2, 64);
                    val += __shfl_xor(val, 4, 64);
                    val += __shfl_xor(val, 8, 64);
                    if (lrow == 0) sred[wc][wr * 32 + mt * 16 + rb + r] = val;
                }
            }
            __syncthreads();
            if (tid < 6) {
                int a = (tid < 3) ? 0 : 1;
                int c = tid - a * 3;
                float b2 = bo2[0];
                float s = 0.0f;
#pragma unroll 4
                for (int n = 0; n < 32; ++n) {
                    int row = a * 32 + n;
                    float fm = sred[0][row] + sred[1][row] + sred[2][row] + sred[3][row] + b2;
                    s += fm * unit[((size_t)((a0 + a) * 32 + n)) * 3 + c];
                }
                out[(size_t)(a0 + a) * 3 + c] = s;
            }
            __syncthreads();   // sred reuse / buf reuse separation for next tile
        }
    }
}

extern "C" void kernel_launch(void* const* d_in, const int* in_sizes, int n_in,
                              void* d_out, int out_size, void* d_ws, size_t ws_size,
                              hipStream_t stream) {
    const int*   Z    = (const int*)d_in[0];
    const int*   nbr  = (const int*)d_in[1];
    const float* dist = (const float*)d_in[2];
    const float* unit = (const float*)d_in[3];
    const float* emb  = (const float*)d_in[4];
    const float* Wnf  = (const float*)d_in[5];
    const float* bnf  = (const float*)d_in[6];
    const float* Wnc  = (const float*)d_in[7];
    const float* bnc  = (const float*)d_in[8];
    const float* Wef  = (const float*)d_in[9];
    const float* bef  = (const float*)d_in[10];
    const float* Wec  = (const float*)d_in[11];
    const float* bec  = (const float*)d_in[12];
    const float* Wo1  = (const float*)d_in[13];
    const float* bo1  = (const float*)d_in[14];
    const float* Wo2  = (const float*)d_in[15];
    const float* bo2  = (const float*)d_in[16];
    float* out = (float*)d_out;

    float* ws = (float*)d_ws;
    float* e   = ws;                               // NEDGE*FE (67 MB)
    float* h0  = e + (size_t)NEDGE * FE;
    float* h1  = h0 + (size_t)NA * FN;
    float* Pi  = h1 + (size_t)NA * FN;             // NA*128*2 (f,c interleaved)
    float* Pj  = Pi + (size_t)NA * FN * 2;         // NA*128*2
    ushort_t* Whi  = (ushort_t*)(Pj + (size_t)NA * FN * 2);  // 12 * 384*128
    ushort_t* Wlo  = Whi + (size_t)12 * WTMAT;
    ushort_t* Wo1h = Wlo + (size_t)12 * WTMAT;               // 64*128
    ushort_t* Wo1l = Wo1h + (size_t)64 * 128;

    k_conv_w<<<36, 256, 0, stream>>>(Wnf, Wnc, Wef, Wec, Whi, Wlo);
    k_conv_wo<<<32, 256, 0, stream>>>(Wo1, Wo1h, Wo1l);
    k_init_h<<<(NA * FN) / 256, 256, 0, stream>>>(Z, emb, h0);

    float* hc = h0;
    float* hn = h1;
    for (int l = 0; l < 3; ++l) {
        const ushort_t* nf_h = Whi + (size_t)(l * 4 + 0) * WTMAT;
        const ushort_t* nf_l = Wlo + (size_t)(l * 4 + 0) * WTMAT;
        const ushort_t* nc_h = Whi + (size_t)(l * 4 + 1) * WTMAT;
        const ushort_t* nc_l = Wlo + (size_t)(l * 4 + 1) * WTMAT;
        const ushort_t* ef_h = Whi + (size_t)(l * 4 + 2) * WTMAT;
        const ushort_t* ef_l = Wlo + (size_t)(l * 4 + 2) * WTMAT;
        const ushort_t* ec_h = Whi + (size_t)(l * 4 + 3) * WTMAT;
        const ushort_t* ec_l = Wlo + (size_t)(l * 4 + 3) * WTMAT;

        // node stage
        k_proj<<<NA / 16, 512, 0, stream>>>(hc, nf_h, nf_l, nc_h, nc_l,
                                            bnf + l * FN, bnc + l * FN, Pi, Pj);
        if (l == 0)
            k_pass<1, 1, 0><<<NA / 8, 512, 0, stream>>>(
                e, e, dist, nbr, Pi, Pj,
                nf_h + EPART, nf_l + EPART, nc_h + EPART, nc_l + EPART,
                hc, hn, nullptr, nullptr, nullptr, nullptr, nullptr, nullptr, nullptr);
        else
            k_pass<1, 0, 0><<<NA / 8, 512, 0, stream>>>(
                e, e, dist, nbr, Pi, Pj,
                nf_h + EPART, nf_l + EPART, nc_h + EPART, nc_l + EPART,
                hc, hn, nullptr, nullptr, nullptr, nullptr, nullptr, nullptr, nullptr);

        // edge stage
        k_proj<<<NA / 16, 512, 0, stream>>>(hn, ef_h, ef_l, ec_h, ec_l,
                                            bef + l * FN, bec + l * FN, Pi, Pj);
        if (l < 2)
            k_pass<0, 0, 0><<<NA / 8, 512, 0, stream>>>(
                e, e, dist, nbr, Pi, Pj,
                ef_h + EPART, ef_l + EPART, ec_h + EPART, ec_l + EPART,
                nullptr, nullptr, nullptr, nullptr, nullptr, nullptr, nullptr, nullptr, nullptr);
        else
            k_pass<0, 0, 1><<<NA / 8, 512, 0, stream>>>(
                e, e, dist, nbr, Pi, Pj,
                ef_h + EPART, ef_l + EPART, ec_h + EPART, ec_l + EPART,
                nullptr, nullptr, Wo1h, Wo1l, bo1, Wo2, bo2, unit, out);

        float* t = hc; hc = hn; hn = t;
    }
}

// Round 8
// 675.702 us; speedup vs baseline: 1.1829x; 1.1829x over previous
//
#include <hip/hip_runtime.h>
#include <math.h>

#define AT 1024
#define NBR 32
#define FN 128
#define FE 128
#define ZIN 384
#define NA 4096              // B*At
#define NEDGE (NA * NBR)     // 131072
#define WSTRIDE (ZIN * FN)   // 49152 floats per layer
#define G_ENDF 5.5f
#define WTMAT (384 * 128)    // converted matrix elements (transposed [n][k])
#define EPART (256 * 128)    // offset of e-part rows within converted matrix

typedef unsigned short ushort_t;
typedef __attribute__((ext_vector_type(8))) short bf16x8;
typedef __attribute__((ext_vector_type(4))) float f32x4;

#define LOG2E 1.4426950408889634f
#define LN2   0.6931471805599453f

__device__ __forceinline__ float fexp(float x) {
    return __builtin_amdgcn_exp2f(x * LOG2E);
}
__device__ __forceinline__ float sigmoid_f(float x) {
    return __builtin_amdgcn_rcpf(1.0f + __builtin_amdgcn_exp2f(-x * LOG2E));
}
__device__ __forceinline__ float softplus_f(float x) {
    float t = __builtin_amdgcn_exp2f(-fabsf(x) * LOG2E);
    return fmaxf(x, 0.0f) + LN2 * __builtin_amdgcn_logf(1.0f + t);
}

__device__ __forceinline__ ushort_t f2bf(float f) {
    unsigned int u = __float_as_uint(f);
    u = (u + 0x7FFFu + ((u >> 16) & 1u)) >> 16;   // RTNE
    return (ushort_t)u;
}
__device__ __forceinline__ float bf2f(ushort_t h) {
    return __uint_as_float(((unsigned int)h) << 16);
}
__device__ __forceinline__ unsigned int cvt_pk_bf16(float a, float b) {
    unsigned int r;
    asm("v_cvt_pk_bf16_f32 %0, %1, %2" : "=v"(r) : "v"(a), "v"(b));
    return r;
}
__device__ __forceinline__ void split2(float a, float b,
                                       unsigned int& hi, unsigned int& lo) {
    hi = cvt_pk_bf16(a, b);
    float ha = __uint_as_float(hi << 16);
    float hb = __uint_as_float(hi & 0xffff0000u);
    lo = cvt_pk_bf16(a - ha, b - hb);
}

// -------- h0[atom][f] = emb[Z[atom]][f] --------
__global__ __launch_bounds__(256) void k_init_h(const int* __restrict__ Z,
                                                const float* __restrict__ emb,
                                                float* __restrict__ h) {
    int idx = blockIdx.x * 256 + threadIdx.x;
    int atom = idx >> 7, f = idx & 127;
    h[idx] = emb[Z[atom] * FN + f];
}

// -------- convert all 12 weight matrices to split-bf16, transposed [n][k] --------
__global__ __launch_bounds__(256) void k_conv_w(const float* __restrict__ Wnf,
                                                const float* __restrict__ Wnc,
                                                const float* __restrict__ Wef,
                                                const float* __restrict__ Wec,
                                                ushort_t* __restrict__ Whi,
                                                ushort_t* __restrict__ Wlo) {
    const int blk = blockIdx.x;         // 0..35
    const int w = blk / 3, p = blk % 3;
    const int l = w >> 2, t = w & 3;
    const float* src = (t == 0 ? Wnf : t == 1 ? Wnc : t == 2 ? Wef : Wec)
                       + (size_t)l * WSTRIDE + (size_t)p * 128 * 128;
    __shared__ float tile[128][129];
    const int tid = threadIdx.x;
    {
        int k = tid >> 1, h = (tid & 1) * 64;
#pragma unroll
        for (int i = 0; i < 16; ++i) {
            float4 v = *(const float4*)&src[k * 128 + h + i * 4];
            tile[k][h + i * 4 + 0] = v.x; tile[k][h + i * 4 + 1] = v.y;
            tile[k][h + i * 4 + 2] = v.z; tile[k][h + i * 4 + 3] = v.w;
        }
    }
    __syncthreads();
    {
        int f = tid >> 1, kh = (tid & 1) * 64;
        size_t orow = (size_t)(w * 384 + p * 128 + f) * 128;
#pragma unroll
        for (int i = 0; i < 64; i += 4) {
            ushort4 ph, pl;
            float x0 = tile[kh + i + 0][f]; ph.x = f2bf(x0); pl.x = f2bf(x0 - bf2f(ph.x));
            float x1 = tile[kh + i + 1][f]; ph.y = f2bf(x1); pl.y = f2bf(x1 - bf2f(ph.y));
            float x2 = tile[kh + i + 2][f]; ph.z = f2bf(x2); pl.z = f2bf(x2 - bf2f(ph.z));
            float x3 = tile[kh + i + 3][f]; ph.w = f2bf(x3); pl.w = f2bf(x3 - bf2f(ph.w));
            *(ushort4*)&Whi[orow + kh + i] = ph;
            *(ushort4*)&Wlo[orow + kh + i] = pl;
        }
    }
}

// -------- Wo1 [128][64] -> Wo1t [64 n][128 k] split bf16 --------
__global__ __launch_bounds__(256) void k_conv_wo(const float* __restrict__ Wo1,
                                                 ushort_t* __restrict__ Wh,
                                                 ushort_t* __restrict__ Wl) {
    int idx = blockIdx.x * 256 + threadIdx.x;  // over 8192
    int n = idx >> 7, k = idx & 127;
    float x = Wo1[k * 64 + n];
    ushort_t h = f2bf(x);
    Wh[idx] = h;
    Wl[idx] = f2bf(x - bf2f(h));
}

// -------- MFMA projection -> interleaved Pi/Pj: [atom][col][{f,c}] --------
__global__ __launch_bounds__(512, 4) void k_proj(
    const float* __restrict__ h,
    const ushort_t* __restrict__ Wah, const ushort_t* __restrict__ Wal,
    const ushort_t* __restrict__ Wbh, const ushort_t* __restrict__ Wbl,
    const float* __restrict__ ba, const float* __restrict__ bb,
    float* __restrict__ Pi, float* __restrict__ Pj) {
    const int tid = threadIdx.x;
    const int a0 = blockIdx.x * 16;
    __shared__ __align__(16) ushort_t sAh[16 * 136];
    __shared__ __align__(16) ushort_t sAl[16 * 136];
    {
        int row = tid >> 5, kq = (tid & 31) * 4;
        float4 v = *(const float4*)&h[(size_t)(a0 + row) * 128 + kq];
        unsigned int h0, l0, h1, l1;
        split2(v.x, v.y, h0, l0);
        split2(v.z, v.w, h1, l1);
        *(uint2*)&sAh[row * 136 + kq] = make_uint2(h0, h1);
        *(uint2*)&sAl[row * 136 + kq] = make_uint2(l0, l1);
    }
    __syncthreads();

    const int w = tid >> 6;
    const int lane = tid & 63;
    const int lrow = lane & 15;
    const int kgrp = (lane >> 4) * 8;

    f32x4 acc[4] = {};
#pragma unroll
    for (int kk = 0; kk < 4; ++kk) {
        const int kbase = kk * 32 + kgrp;
        bf16x8 ah = *(const bf16x8*)&sAh[lrow * 136 + kbase];
        bf16x8 al = *(const bf16x8*)&sAl[lrow * 136 + kbase];
#pragma unroll
        for (int nt = 0; nt < 4; ++nt) {
            int r512 = w * 64 + nt * 16 + lrow;
            const ushort_t* bh_p = (r512 < 256) ? (Wah + (size_t)r512 * 128)
                                                : (Wbh + (size_t)(r512 - 256) * 128);
            const ushort_t* bl_p = (r512 < 256) ? (Wal + (size_t)r512 * 128)
                                                : (Wbl + (size_t)(r512 - 256) * 128);
            bf16x8 bh = *(const bf16x8*)&bh_p[kbase];
            bf16x8 bl = *(const bf16x8*)&bl_p[kbase];
            acc[nt] = __builtin_amdgcn_mfma_f32_16x16x32_bf16(ah, bh, acc[nt], 0, 0, 0);
            acc[nt] = __builtin_amdgcn_mfma_f32_16x16x32_bf16(ah, bl, acc[nt], 0, 0, 0);
            acc[nt] = __builtin_amdgcn_mfma_f32_16x16x32_bf16(al, bh, acc[nt], 0, 0, 0);
        }
    }

    const int arr = w >> 1;
    float* dst = (arr & 1) ? Pj : Pi;
    const int slot = arr >> 1;
    const int rb = (lane >> 4) * 4;
#pragma unroll
    for (int nt = 0; nt < 4; ++nt) {
        int f = (w & 1) * 64 + nt * 16 + lrow;
        float bs = (arr == 0) ? ba[f] : (arr == 2) ? bb[f] : 0.0f;
#pragma unroll
        for (int r = 0; r < 4; ++r) {
            int row = rb + r;
            dst[((size_t)(a0 + row) * 128 + f) * 2 + slot] = acc[nt][r] + bs;
        }
    }
}

// -------- fused split-bf16 MFMA pass --------
// block = 2 atoms = 64 edge rows, 512 thr = 8 waves (2 row-grp x 4 col-grp)
// launch_bounds (512,2): VGPR cap 256 so the Pi/Pj prefetch + weight-load
// batching actually stays in registers (r6 at (512,4) collapsed to 48 VGPR
// and serialized all latency; r7's pipeline spilled to scratch).
template <int NODE, int FIRST, int FUSE>
__global__ __launch_bounds__(512, 2) void k_pass(
    const float* __restrict__ e_g, float* __restrict__ e_out,
    const float* __restrict__ dist, const int* __restrict__ nbr,
    const float* __restrict__ Pi, const float* __restrict__ Pj,
    const ushort_t* __restrict__ Wfh, const ushort_t* __restrict__ Wfl,
    const ushort_t* __restrict__ Wch, const ushort_t* __restrict__ Wcl,
    const float* __restrict__ h_old, float* __restrict__ h_new,
    const ushort_t* __restrict__ Wo1h, const ushort_t* __restrict__ Wo1l,
    const float* __restrict__ bo1, const float* __restrict__ Wo2,
    const float* __restrict__ bo2, const float* __restrict__ unit,
    float* __restrict__ out) {
    const int tid = threadIdx.x;
    const int a0 = blockIdx.x * 2;
    const int base = (a0 >> 10) << 10;

    __shared__ __align__(16) ushort_t sAh[64 * 136];
    __shared__ __align__(16) ushort_t sAl[64 * 136];
    __shared__ int snbr[64];
    __shared__ float sred[4][64];

    // ---- stage e (or generate from dist) -> split bf16 LDS ----
    {
        int row = tid >> 3, kq = (tid & 7) * 16;
        size_t eoff = ((size_t)(a0 * 32 + row)) * 128 + kq;
        float v[16];
        if (FIRST) {
            const float delta = G_ENDF / 127.0f;
            const float coeff = -0.5f / (delta * delta);
            float d = dist[a0 * 32 + row];
#pragma unroll
            for (int i = 0; i < 16; ++i) {
                float x = d - (float)(kq + i) * delta;
                v[i] = fexp(coeff * x * x);
            }
#pragma unroll
            for (int i = 0; i < 4; ++i)
                *(float4*)&e_out[eoff + i * 4] =
                    make_float4(v[i * 4], v[i * 4 + 1], v[i * 4 + 2], v[i * 4 + 3]);
        } else {
#pragma unroll
            for (int i = 0; i < 4; ++i) {
                float4 t = *(const float4*)&e_g[eoff + i * 4];
                v[i * 4] = t.x; v[i * 4 + 1] = t.y; v[i * 4 + 2] = t.z; v[i * 4 + 3] = t.w;
            }
        }
#pragma unroll
        for (int i = 0; i < 4; ++i) {
            unsigned int h0, l0, h1, l1;
            split2(v[i * 4 + 0], v[i * 4 + 1], h0, l0);
            split2(v[i * 4 + 2], v[i * 4 + 3], h1, l1);
            *(uint2*)&sAh[row * 136 + kq + i * 4] = make_uint2(h0, h1);
            *(uint2*)&sAl[row * 136 + kq + i * 4] = make_uint2(l0, l1);
        }
    }
    if (tid < 64) snbr[tid] = nbr[a0 * 32 + tid];
    __syncthreads();

    const int w = tid >> 6;
    const int lane = tid & 63;
    const int wr = w >> 2;        // 0..1 : 32-row group = one atom
    const int wc = w & 3;         // 0..3 : 32-col group
    const int lrow = lane & 15;
    const int kgrp = (lane >> 4) * 8;
    const int rb = (lane >> 4) * 4;

    // ---- prefetch ALL epilogue operands; sched_barrier pins issue here ----
    float2 pi_[2];
    float2 pj_[2][8];
#pragma unroll
    for (int nt = 0; nt < 2; ++nt) {
        const int nn = wc * 32 + nt * 16 + lrow;
        pi_[nt] = *(const float2*)&Pi[((size_t)(a0 + wr) * 128 + nn) * 2];
#pragma unroll
        for (int mt = 0; mt < 2; ++mt)
#pragma unroll
            for (int r = 0; r < 4; ++r) {
                const int rl = wr * 32 + mt * 16 + rb + r;
                const int j = base + snbr[rl];
                pj_[nt][mt * 4 + r] = *(const float2*)&Pj[((size_t)j * 128 + nn) * 2];
            }
    }
    __builtin_amdgcn_sched_barrier(0);

    f32x4 accf[2][2] = {};
    f32x4 accc[2][2] = {};

#pragma unroll
    for (int kk = 0; kk < 4; ++kk) {
        const int kbase = kk * 32 + kgrp;
        bf16x8 ah[2], al[2];
#pragma unroll
        for (int mt = 0; mt < 2; ++mt) {
            ah[mt] = *(const bf16x8*)&sAh[(wr * 32 + mt * 16 + lrow) * 136 + kbase];
            al[mt] = *(const bf16x8*)&sAl[(wr * 32 + mt * 16 + lrow) * 136 + kbase];
        }
#pragma unroll
        for (int nt = 0; nt < 2; ++nt) {
            const int nn = wc * 32 + nt * 16 + lrow;
            bf16x8 bfh = *(const bf16x8*)&Wfh[(size_t)nn * 128 + kbase];
            bf16x8 bfl = *(const bf16x8*)&Wfl[(size_t)nn * 128 + kbase];
            bf16x8 bch = *(const bf16x8*)&Wch[(size_t)nn * 128 + kbase];
            bf16x8 bcl = *(const bf16x8*)&Wcl[(size_t)nn * 128 + kbase];
#pragma unroll
            for (int mt = 0; mt < 2; ++mt) {
                accf[mt][nt] = __builtin_amdgcn_mfma_f32_16x16x32_bf16(ah[mt], bfh, accf[mt][nt], 0, 0, 0);
                accf[mt][nt] = __builtin_amdgcn_mfma_f32_16x16x32_bf16(ah[mt], bfl, accf[mt][nt], 0, 0, 0);
                accf[mt][nt] = __builtin_amdgcn_mfma_f32_16x16x32_bf16(al[mt], bfh, accf[mt][nt], 0, 0, 0);
                accc[mt][nt] = __builtin_amdgcn_mfma_f32_16x16x32_bf16(ah[mt], bch, accc[mt][nt], 0, 0, 0);
                accc[mt][nt] = __builtin_amdgcn_mfma_f32_16x16x32_bf16(ah[mt], bcl, accc[mt][nt], 0, 0, 0);
                accc[mt][nt] = __builtin_amdgcn_mfma_f32_16x16x32_bf16(al[mt], bch, accc[mt][nt], 0, 0, 0);
            }
        }
    }

    if (FUSE) __syncthreads();   // all waves done reading A before epilogue rewrites it

    // ---- epilogue (e reconstructed from LDS split pair: err ~2^-17 rel) ----
    float hsum[2] = {0.0f, 0.0f};
#pragma unroll
    for (int nt = 0; nt < 2; ++nt) {
        const int nn = wc * 32 + nt * 16 + lrow;
#pragma unroll
        for (int mt = 0; mt < 2; ++mt) {
#pragma unroll
            for (int r = 0; r < 4; ++r) {
                const int rl = wr * 32 + mt * 16 + rb + r;
                const int idx = mt * 4 + r;
                float cf = accf[mt][nt][r] + pi_[nt].x + pj_[nt][idx].x;
                float cc = accc[mt][nt][r] + pi_[nt].y + pj_[nt][idx].y;
                float msg = sigmoid_f(cf) * softplus_f(cc);
                if (NODE) {
                    hsum[nt] += msg;
                } else {
                    const int lidx = rl * 136 + nn;
                    float eold = bf2f(sAh[lidx]) + bf2f(sAl[lidx]);
                    float enew = eold + msg;
                    if (FUSE) {
                        ushort_t hh = f2bf(enew);
                        sAh[lidx] = hh;
                        sAl[lidx] = f2bf(enew - bf2f(hh));
                    } else {
                        e_out[((size_t)(a0 * 32 + rl)) * 128 + nn] = enew;
                    }
                }
            }
        }
    }

    if (NODE) {
#pragma unroll
        for (int nt = 0; nt < 2; ++nt) {
            float v = hsum[nt];
            v += __shfl_xor(v, 16, 64);
            v += __shfl_xor(v, 32, 64);
            if (lane < 16) {
                int col = wc * 32 + nt * 16 + lane;
                h_new[(size_t)(a0 + wr) * 128 + col] =
                    h_old[(size_t)(a0 + wr) * 128 + col] + v;
            }
        }
    }

    if (FUSE) {
        __syncthreads();   // e_new fully in LDS
        f32x4 acco[2] = {};
        const int col = wc * 16 + lrow;
#pragma unroll
        for (int kk = 0; kk < 4; ++kk) {
            const int kbase = kk * 32 + kgrp;
            bf16x8 bh = *(const bf16x8*)&Wo1h[(size_t)col * 128 + kbase];
            bf16x8 bl = *(const bf16x8*)&Wo1l[(size_t)col * 128 + kbase];
#pragma unroll
            for (int mt = 0; mt < 2; ++mt) {
                bf16x8 ah = *(const bf16x8*)&sAh[(wr * 32 + mt * 16 + lrow) * 136 + kbase];
                bf16x8 al = *(const bf16x8*)&sAl[(wr * 32 + mt * 16 + lrow) * 136 + kbase];
                acco[mt] = __builtin_amdgcn_mfma_f32_16x16x32_bf16(ah, bh, acco[mt], 0, 0, 0);
                acco[mt] = __builtin_amdgcn_mfma_f32_16x16x32_bf16(ah, bl, acco[mt], 0, 0, 0);
                acco[mt] = __builtin_amdgcn_mfma_f32_16x16x32_bf16(al, bh, acco[mt], 0, 0, 0);
            }
        }
        const float b1 = bo1[col];
        const float w2 = Wo2[col];
#pragma unroll
        for (int mt = 0; mt < 2; ++mt) {
#pragma unroll
            for (int r = 0; r < 4; ++r) {
                float val = softplus_f(acco[mt][r] + b1) * w2;
                val += __shfl_xor(val, 1, 64);
                val += __shfl_xor(val, 2, 64);
                val += __shfl_xor(val, 4, 64);
                val += __shfl_xor(val, 8, 64);
                if (lrow == 0) sred[wc][wr * 32 + mt * 16 + rb + r] = val;
            }
        }
        __syncthreads();
        if (tid < 6) {
            int a = (tid < 3) ? 0 : 1;
            int c = tid - a * 3;
            float b2 = bo2[0];
            float s = 0.0f;
#pragma unroll 4
            for (int n = 0; n < 32; ++n) {
                int row = a * 32 + n;
                float fm = sred[0][row] + sred[1][row] + sred[2][row] + sred[3][row] + b2;
                s += fm * unit[((size_t)((a0 + a) * 32 + n)) * 3 + c];
            }
            out[(size_t)(a0 + a) * 3 + c] = s;
        }
    }
}

extern "C" void kernel_launch(void* const* d_in, const int* in_sizes, int n_in,
                              void* d_out, int out_size, void* d_ws, size_t ws_size,
                              hipStream_t stream) {
    const int*   Z    = (const int*)d_in[0];
    const int*   nbr  = (const int*)d_in[1];
    const float* dist = (const float*)d_in[2];
    const float* unit = (const float*)d_in[3];
    const float* emb  = (const float*)d_in[4];
    const float* Wnf  = (const float*)d_in[5];
    const float* bnf  = (const float*)d_in[6];
    const float* Wnc  = (const float*)d_in[7];
    const float* bnc  = (const float*)d_in[8];
    const float* Wef  = (const float*)d_in[9];
    const float* bef  = (const float*)d_in[10];
    const float* Wec  = (const float*)d_in[11];
    const float* bec  = (const float*)d_in[12];
    const float* Wo1  = (const float*)d_in[13];
    const float* bo1  = (const float*)d_in[14];
    const float* Wo2  = (const float*)d_in[15];
    const float* bo2  = (const float*)d_in[16];
    float* out = (float*)d_out;

    float* ws = (float*)d_ws;
    float* e   = ws;                               // NEDGE*FE (67 MB)
    float* h0  = e + (size_t)NEDGE * FE;
    float* h1  = h0 + (size_t)NA * FN;
    float* Pi  = h1 + (size_t)NA * FN;             // NA*128*2 (f,c interleaved)
    float* Pj  = Pi + (size_t)NA * FN * 2;         // NA*128*2
    ushort_t* Whi  = (ushort_t*)(Pj + (size_t)NA * FN * 2);  // 12 * 384*128
    ushort_t* Wlo  = Whi + (size_t)12 * WTMAT;
    ushort_t* Wo1h = Wlo + (size_t)12 * WTMAT;               // 64*128
    ushort_t* Wo1l = Wo1h + (size_t)64 * 128;

    k_conv_w<<<36, 256, 0, stream>>>(Wnf, Wnc, Wef, Wec, Whi, Wlo);
    k_conv_wo<<<32, 256, 0, stream>>>(Wo1, Wo1h, Wo1l);
    k_init_h<<<(NA * FN) / 256, 256, 0, stream>>>(Z, emb, h0);

    float* hc = h0;
    float* hn = h1;
    for (int l = 0; l < 3; ++l) {
        const ushort_t* nf_h = Whi + (size_t)(l * 4 + 0) * WTMAT;
        const ushort_t* nf_l = Wlo + (size_t)(l * 4 + 0) * WTMAT;
        const ushort_t* nc_h = Whi + (size_t)(l * 4 + 1) * WTMAT;
        const ushort_t* nc_l = Wlo + (size_t)(l * 4 + 1) * WTMAT;
        const ushort_t* ef_h = Whi + (size_t)(l * 4 + 2) * WTMAT;
        const ushort_t* ef_l = Wlo + (size_t)(l * 4 + 2) * WTMAT;
        const ushort_t* ec_h = Whi + (size_t)(l * 4 + 3) * WTMAT;
        const ushort_t* ec_l = Wlo + (size_t)(l * 4 + 3) * WTMAT;

        // node stage
        k_proj<<<NA / 16, 512, 0, stream>>>(hc, nf_h, nf_l, nc_h, nc_l,
                                            bnf + l * FN, bnc + l * FN, Pi, Pj);
        if (l == 0)
            k_pass<1, 1, 0><<<NA / 2, 512, 0, stream>>>(
                e, e, dist, nbr, Pi, Pj,
                nf_h + EPART, nf_l + EPART, nc_h + EPART, nc_l + EPART,
                hc, hn, nullptr, nullptr, nullptr, nullptr, nullptr, nullptr, nullptr);
        else
            k_pass<1, 0, 0><<<NA / 2, 512, 0, stream>>>(
                e, e, dist, nbr, Pi, Pj,
                nf_h + EPART, nf_l + EPART, nc_h + EPART, nc_l + EPART,
                hc, hn, nullptr, nullptr, nullptr, nullptr, nullptr, nullptr, nullptr);

        // edge stage
        k_proj<<<NA / 16, 512, 0, stream>>>(hn, ef_h, ef_l, ec_h, ec_l,
                                            bef + l * FN, bec + l * FN, Pi, Pj);
        if (l < 2)
            k_pass<0, 0, 0><<<NA / 2, 512, 0, stream>>>(
                e, e, dist, nbr, Pi, Pj,
                ef_h + EPART, ef_l + EPART, ec_h + EPART, ec_l + EPART,
                nullptr, nullptr, nullptr, nullptr, nullptr, nullptr, nullptr, nullptr, nullptr);
        else
            k_pass<0, 0, 1><<<NA / 2, 512, 0, stream>>>(
                e, e, dist, nbr, Pi, Pj,
                ef_h + EPART, ef_l + EPART, ec_h + EPART, ec_l + EPART,
                nullptr, nullptr, Wo1h, Wo1l, bo1, Wo2, bo2, unit, out);

        float* t = hc; hc = hn; hn = t;
    }
}

// Round 10
// 657.890 us; speedup vs baseline: 1.2149x; 1.0271x over previous
//
#include <hip/hip_runtime.h>
#include <math.h>

#define AT 1024
#define NBR 32
#define FN 128
#define FE 128
#define ZIN 384
#define NA 4096              // B*At
#define NEDGE (NA * NBR)     // 131072
#define WSTRIDE (ZIN * FN)   // 49152 floats per layer
#define G_ENDF 5.5f
#define WTMAT (384 * 128)    // converted matrix elements (transposed [n][k])
#define EPART (256 * 128)    // offset of e-part rows within converted matrix

typedef unsigned short ushort_t;
typedef __attribute__((ext_vector_type(8))) short bf16x8;
typedef __attribute__((ext_vector_type(4))) float f32x4;

#define LOG2E 1.4426950408889634f
#define LN2   0.6931471805599453f

__device__ __forceinline__ float fexp(float x) {
    return __builtin_amdgcn_exp2f(x * LOG2E);
}
__device__ __forceinline__ float sigmoid_f(float x) {
    return __builtin_amdgcn_rcpf(1.0f + __builtin_amdgcn_exp2f(-x * LOG2E));
}
__device__ __forceinline__ float softplus_f(float x) {
    float t = __builtin_amdgcn_exp2f(-fabsf(x) * LOG2E);
    return fmaxf(x, 0.0f) + LN2 * __builtin_amdgcn_logf(1.0f + t);
}

__device__ __forceinline__ ushort_t f2bf(float f) {
    unsigned int u = __float_as_uint(f);
    u = (u + 0x7FFFu + ((u >> 16) & 1u)) >> 16;   // RTNE
    return (ushort_t)u;
}
__device__ __forceinline__ float bf2f(ushort_t h) {
    return __uint_as_float(((unsigned int)h) << 16);
}
__device__ __forceinline__ unsigned int cvt_pk_bf16(float a, float b) {
    unsigned int r;
    asm("v_cvt_pk_bf16_f32 %0, %1, %2" : "=v"(r) : "v"(a), "v"(b));
    return r;
}
__device__ __forceinline__ void split2(float a, float b,
                                       unsigned int& hi, unsigned int& lo) {
    hi = cvt_pk_bf16(a, b);
    float ha = __uint_as_float(hi << 16);
    float hb = __uint_as_float(hi & 0xffff0000u);
    lo = cvt_pk_bf16(a - ha, b - hb);
}

// -------- h0[atom][f] = emb[Z[atom]][f] --------
__global__ __launch_bounds__(256) void k_init_h(const int* __restrict__ Z,
                                                const float* __restrict__ emb,
                                                float* __restrict__ h) {
    int idx = blockIdx.x * 256 + threadIdx.x;
    int atom = idx >> 7, f = idx & 127;
    h[idx] = emb[Z[atom] * FN + f];
}

// -------- convert all 12 weight matrices to split-bf16, transposed [n][k] --------
__global__ __launch_bounds__(256) void k_conv_w(const float* __restrict__ Wnf,
                                                const float* __restrict__ Wnc,
                                                const float* __restrict__ Wef,
                                                const float* __restrict__ Wec,
                                                ushort_t* __restrict__ Whi,
                                                ushort_t* __restrict__ Wlo) {
    const int blk = blockIdx.x;         // 0..35
    const int w = blk / 3, p = blk % 3;
    const int l = w >> 2, t = w & 3;
    const float* src = (t == 0 ? Wnf : t == 1 ? Wnc : t == 2 ? Wef : Wec)
                       + (size_t)l * WSTRIDE + (size_t)p * 128 * 128;
    __shared__ float tile[128][129];
    const int tid = threadIdx.x;
    {
        int k = tid >> 1, h = (tid & 1) * 64;
#pragma unroll
        for (int i = 0; i < 16; ++i) {
            float4 v = *(const float4*)&src[k * 128 + h + i * 4];
            tile[k][h + i * 4 + 0] = v.x; tile[k][h + i * 4 + 1] = v.y;
            tile[k][h + i * 4 + 2] = v.z; tile[k][h + i * 4 + 3] = v.w;
        }
    }
    __syncthreads();
    {
        int f = tid >> 1, kh = (tid & 1) * 64;
        size_t orow = (size_t)(w * 384 + p * 128 + f) * 128;
#pragma unroll
        for (int i = 0; i < 64; i += 4) {
            ushort4 ph, pl;
            float x0 = tile[kh + i + 0][f]; ph.x = f2bf(x0); pl.x = f2bf(x0 - bf2f(ph.x));
            float x1 = tile[kh + i + 1][f]; ph.y = f2bf(x1); pl.y = f2bf(x1 - bf2f(ph.y));
            float x2 = tile[kh + i + 2][f]; ph.z = f2bf(x2); pl.z = f2bf(x2 - bf2f(ph.z));
            float x3 = tile[kh + i + 3][f]; ph.w = f2bf(x3); pl.w = f2bf(x3 - bf2f(ph.w));
            *(ushort4*)&Whi[orow + kh + i] = ph;
            *(ushort4*)&Wlo[orow + kh + i] = pl;
        }
    }
}

// -------- Wo1 [128][64] -> Wo1t [64 n][128 k] split bf16 --------
__global__ __launch_bounds__(256) void k_conv_wo(const float* __restrict__ Wo1,
                                                 ushort_t* __restrict__ Wh,
                                                 ushort_t* __restrict__ Wl) {
    int idx = blockIdx.x * 256 + threadIdx.x;  // over 8192
    int n = idx >> 7, k = idx & 127;
    float x = Wo1[k * 64 + n];
    ushort_t h = f2bf(x);
    Wh[idx] = h;
    Wl[idx] = f2bf(x - bf2f(h));
}

// -------- MFMA projection -> interleaved Pi/Pj: [atom][col][{f,c}] --------
__global__ __launch_bounds__(512, 4) void k_proj(
    const float* __restrict__ h,
    const ushort_t* __restrict__ Wah, const ushort_t* __restrict__ Wal,
    const ushort_t* __restrict__ Wbh, const ushort_t* __restrict__ Wbl,
    const float* __restrict__ ba, const float* __restrict__ bb,
    float* __restrict__ Pi, float* __restrict__ Pj) {
    const int tid = threadIdx.x;
    const int a0 = blockIdx.x * 16;
    __shared__ __align__(16) ushort_t sAh[16 * 136];
    __shared__ __align__(16) ushort_t sAl[16 * 136];
    {
        int row = tid >> 5, kq = (tid & 31) * 4;
        float4 v = *(const float4*)&h[(size_t)(a0 + row) * 128 + kq];
        unsigned int h0, l0, h1, l1;
        split2(v.x, v.y, h0, l0);
        split2(v.z, v.w, h1, l1);
        *(uint2*)&sAh[row * 136 + kq] = make_uint2(h0, h1);
        *(uint2*)&sAl[row * 136 + kq] = make_uint2(l0, l1);
    }
    __syncthreads();

    const int w = tid >> 6;
    const int lane = tid & 63;
    const int lrow = lane & 15;
    const int kgrp = (lane >> 4) * 8;

    f32x4 acc[4] = {};
#pragma unroll
    for (int kk = 0; kk < 4; ++kk) {
        const int kbase = kk * 32 + kgrp;
        bf16x8 ah = *(const bf16x8*)&sAh[lrow * 136 + kbase];
        bf16x8 al = *(const bf16x8*)&sAl[lrow * 136 + kbase];
#pragma unroll
        for (int nt = 0; nt < 4; ++nt) {
            int r512 = w * 64 + nt * 16 + lrow;
            const ushort_t* bh_p = (r512 < 256) ? (Wah + (size_t)r512 * 128)
                                                : (Wbh + (size_t)(r512 - 256) * 128);
            const ushort_t* bl_p = (r512 < 256) ? (Wal + (size_t)r512 * 128)
                                                : (Wbl + (size_t)(r512 - 256) * 128);
            bf16x8 bh = *(const bf16x8*)&bh_p[kbase];
            bf16x8 bl = *(const bf16x8*)&bl_p[kbase];
            acc[nt] = __builtin_amdgcn_mfma_f32_16x16x32_bf16(ah, bh, acc[nt], 0, 0, 0);
            acc[nt] = __builtin_amdgcn_mfma_f32_16x16x32_bf16(ah, bl, acc[nt], 0, 0, 0);
            acc[nt] = __builtin_amdgcn_mfma_f32_16x16x32_bf16(al, bh, acc[nt], 0, 0, 0);
        }
    }

    const int arr = w >> 1;
    float* dst = (arr & 1) ? Pj : Pi;
    const int slot = arr >> 1;
    const int rb = (lane >> 4) * 4;
#pragma unroll
    for (int nt = 0; nt < 4; ++nt) {
        int f = (w & 1) * 64 + nt * 16 + lrow;
        float bs = (arr == 0) ? ba[f] : (arr == 2) ? bb[f] : 0.0f;
#pragma unroll
        for (int r = 0; r < 4; ++r) {
            int row = rb + r;
            dst[((size_t)(a0 + row) * 128 + f) * 2 + slot] = acc[nt][r] + bs;
        }
    }
}

// -------- fused split-bf16 MFMA pass, small-block/high-TLP variant --------
// block = 1 atom = 32 edge rows, 256 thr = 4 waves (each wave = one 32-col group).
// 18 KB LDS -> up to 6 independent blocks/CU; latency hidden by TLP, not ILP.
template <int NODE, int FIRST, int FUSE>
__global__ __launch_bounds__(256, 6) void k_pass(
    const float* __restrict__ e_g, float* __restrict__ e_out,
    const float* __restrict__ dist, const int* __restrict__ nbr,
    const float* __restrict__ Pi, const float* __restrict__ Pj,
    const ushort_t* __restrict__ Wfh, const ushort_t* __restrict__ Wfl,
    const ushort_t* __restrict__ Wch, const ushort_t* __restrict__ Wcl,
    const float* __restrict__ h_old, float* __restrict__ h_new,
    const ushort_t* __restrict__ Wo1h, const ushort_t* __restrict__ Wo1l,
    const float* __restrict__ bo1, const float* __restrict__ Wo2,
    const float* __restrict__ bo2, const float* __restrict__ unit,
    float* __restrict__ out) {
    const int tid = threadIdx.x;
    const int a0 = blockIdx.x;                // one atom per block
    const int base = (a0 >> 10) << 10;

    __shared__ __align__(16) ushort_t sAh[32 * 136];
    __shared__ __align__(16) ushort_t sAl[32 * 136];
    __shared__ int snbr[32];
    __shared__ float sred[4][32];

    // ---- stage e (or generate from dist) -> split bf16 LDS ----
    {
        int row = tid >> 3, kq = (tid & 7) * 16;
        size_t eoff = ((size_t)(a0 * 32 + row)) * 128 + kq;
        float v[16];
        if (FIRST) {
            const float delta = G_ENDF / 127.0f;
            const float coeff = -0.5f / (delta * delta);
            float d = dist[a0 * 32 + row];
#pragma unroll
            for (int i = 0; i < 16; ++i) {
                float x = d - (float)(kq + i) * delta;
                v[i] = fexp(coeff * x * x);
            }
#pragma unroll
            for (int i = 0; i < 4; ++i)
                *(float4*)&e_out[eoff + i * 4] =
                    make_float4(v[i * 4], v[i * 4 + 1], v[i * 4 + 2], v[i * 4 + 3]);
        } else {
#pragma unroll
            for (int i = 0; i < 4; ++i) {
                float4 t = *(const float4*)&e_g[eoff + i * 4];
                v[i * 4] = t.x; v[i * 4 + 1] = t.y; v[i * 4 + 2] = t.z; v[i * 4 + 3] = t.w;
            }
        }
#pragma unroll
        for (int i = 0; i < 4; ++i) {
            unsigned int h0, l0, h1, l1;
            split2(v[i * 4 + 0], v[i * 4 + 1], h0, l0);
            split2(v[i * 4 + 2], v[i * 4 + 3], h1, l1);
            *(uint2*)&sAh[row * 136 + kq + i * 4] = make_uint2(h0, h1);
            *(uint2*)&sAl[row * 136 + kq + i * 4] = make_uint2(l0, l1);
        }
    }
    if (tid < 32) snbr[tid] = nbr[a0 * 32 + tid];
    __syncthreads();

    const int w = tid >> 6;       // 0..3 : 32-col group
    const int lane = tid & 63;
    const int lrow = lane & 15;
    const int kgrp = (lane >> 4) * 8;
    const int rb = (lane >> 4) * 4;

    f32x4 accf[2][2] = {};
    f32x4 accc[2][2] = {};

#pragma unroll
    for (int kk = 0; kk < 4; ++kk) {
        const int kbase = kk * 32 + kgrp;
        bf16x8 ah[2], al[2];
#pragma unroll
        for (int mt = 0; mt < 2; ++mt) {
            ah[mt] = *(const bf16x8*)&sAh[(mt * 16 + lrow) * 136 + kbase];
            al[mt] = *(const bf16x8*)&sAl[(mt * 16 + lrow) * 136 + kbase];
        }
#pragma unroll
        for (int nt = 0; nt < 2; ++nt) {
            const int nn = w * 32 + nt * 16 + lrow;
            bf16x8 bfh = *(const bf16x8*)&Wfh[(size_t)nn * 128 + kbase];
            bf16x8 bfl = *(const bf16x8*)&Wfl[(size_t)nn * 128 + kbase];
            bf16x8 bch = *(const bf16x8*)&Wch[(size_t)nn * 128 + kbase];
            bf16x8 bcl = *(const bf16x8*)&Wcl[(size_t)nn * 128 + kbase];
#pragma unroll
            for (int mt = 0; mt < 2; ++mt) {
                accf[mt][nt] = __builtin_amdgcn_mfma_f32_16x16x32_bf16(ah[mt], bfh, accf[mt][nt], 0, 0, 0);
                accf[mt][nt] = __builtin_amdgcn_mfma_f32_16x16x32_bf16(ah[mt], bfl, accf[mt][nt], 0, 0, 0);
                accf[mt][nt] = __builtin_amdgcn_mfma_f32_16x16x32_bf16(al[mt], bfh, accf[mt][nt], 0, 0, 0);
                accc[mt][nt] = __builtin_amdgcn_mfma_f32_16x16x32_bf16(ah[mt], bch, accc[mt][nt], 0, 0, 0);
                accc[mt][nt] = __builtin_amdgcn_mfma_f32_16x16x32_bf16(ah[mt], bcl, accc[mt][nt], 0, 0, 0);
                accc[mt][nt] = __builtin_amdgcn_mfma_f32_16x16x32_bf16(al[mt], bch, accc[mt][nt], 0, 0, 0);
            }
        }
    }

    if (FUSE) __syncthreads();   // all waves done reading A before epilogue rewrites it

    // ---- epilogue (e reconstructed from LDS split pair: err ~2^-17 rel) ----
    float hsum[2] = {0.0f, 0.0f};
#pragma unroll
    for (int nt = 0; nt < 2; ++nt) {
        const int nn = w * 32 + nt * 16 + lrow;
        const float2 piv = *(const float2*)&Pi[((size_t)a0 * 128 + nn) * 2];
#pragma unroll
        for (int mt = 0; mt < 2; ++mt) {
#pragma unroll
            for (int r = 0; r < 4; ++r) {
                const int rl = mt * 16 + rb + r;
                const int j = base + snbr[rl];
                const float2 pjv = *(const float2*)&Pj[((size_t)j * 128 + nn) * 2];
                float cf = accf[mt][nt][r] + piv.x + pjv.x;
                float cc = accc[mt][nt][r] + piv.y + pjv.y;
                float msg = sigmoid_f(cf) * softplus_f(cc);
                if (NODE) {
                    hsum[nt] += msg;
                } else {
                    const int lidx = rl * 136 + nn;
                    float eold = bf2f(sAh[lidx]) + bf2f(sAl[lidx]);
                    float enew = eold + msg;
                    if (FUSE) {
                        ushort_t hh = f2bf(enew);
                        sAh[lidx] = hh;
                        sAl[lidx] = f2bf(enew - bf2f(hh));
                    } else {
                        e_out[((size_t)(a0 * 32 + rl)) * 128 + nn] = enew;
                    }
                }
            }
        }
    }

    if (NODE) {
#pragma unroll
        for (int nt = 0; nt < 2; ++nt) {
            float v = hsum[nt];
            v += __shfl_xor(v, 16, 64);
            v += __shfl_xor(v, 32, 64);
            if (lane < 16) {
                int col = w * 32 + nt * 16 + lane;
                h_new[(size_t)a0 * 128 + col] =
                    h_old[(size_t)a0 * 128 + col] + v;
            }
        }
    }

    if (FUSE) {
        __syncthreads();   // e_new fully in LDS
        f32x4 acco[2] = {};
        const int col = w * 16 + lrow;     // 64 head cols over 4 waves
#pragma unroll
        for (int kk = 0; kk < 4; ++kk) {
            const int kbase = kk * 32 + kgrp;
            bf16x8 bh = *(const bf16x8*)&Wo1h[(size_t)col * 128 + kbase];
            bf16x8 bl = *(const bf16x8*)&Wo1l[(size_t)col * 128 + kbase];
#pragma unroll
            for (int mt = 0; mt < 2; ++mt) {
                bf16x8 ah = *(const bf16x8*)&sAh[(mt * 16 + lrow) * 136 + kbase];
                bf16x8 al = *(const bf16x8*)&sAl[(mt * 16 + lrow) * 136 + kbase];
                acco[mt] = __builtin_amdgcn_mfma_f32_16x16x32_bf16(ah, bh, acco[mt], 0, 0, 0);
                acco[mt] = __builtin_amdgcn_mfma_f32_16x16x32_bf16(ah, bl, acco[mt], 0, 0, 0);
                acco[mt] = __builtin_amdgcn_mfma_f32_16x16x32_bf16(al, bh, acco[mt], 0, 0, 0);
            }
        }
        const float b1 = bo1[col];
        const float w2 = Wo2[col];
#pragma unroll
        for (int mt = 0; mt < 2; ++mt) {
#pragma unroll
            for (int r = 0; r < 4; ++r) {
                float val = softplus_f(acco[mt][r] + b1) * w2;
                val += __shfl_xor(val, 1, 64);
                val += __shfl_xor(val, 2, 64);
                val += __shfl_xor(val, 4, 64);
                val += __shfl_xor(val, 8, 64);
                if (lrow == 0) sred[w][mt * 16 + rb + r] = val;
            }
        }
        __syncthreads();
        if (tid < 3) {
            float b2 = bo2[0];
            float s = 0.0f;
#pragma unroll 4
            for (int n = 0; n < 32; ++n) {
                float fm = sred[0][n] + sred[1][n] + sred[2][n] + sred[3][n] + b2;
                s += fm * unit[((size_t)(a0 * 32 + n)) * 3 + tid];
            }
            out[(size_t)a0 * 3 + tid] = s;
        }
    }
}

extern "C" void kernel_launch(void* const* d_in, const int* in_sizes, int n_in,
                              void* d_out, int out_size, void* d_ws, size_t ws_size,
                              hipStream_t stream) {
    const int*   Z    = (const int*)d_in[0];
    const int*   nbr  = (const int*)d_in[1];
    const float* dist = (const float*)d_in[2];
    const float* unit = (const float*)d_in[3];
    const float* emb  = (const float*)d_in[4];
    const float* Wnf  = (const float*)d_in[5];
    const float* bnf  = (const float*)d_in[6];
    const float* Wnc  = (const float*)d_in[7];
    const float* bnc  = (const float*)d_in[8];
    const float* Wef  = (const float*)d_in[9];
    const float* bef  = (const float*)d_in[10];
    const float* Wec  = (const float*)d_in[11];
    const float* bec  = (const float*)d_in[12];
    const float* Wo1  = (const float*)d_in[13];
    const float* bo1  = (const float*)d_in[14];
    const float* Wo2  = (const float*)d_in[15];
    const float* bo2  = (const float*)d_in[16];
    float* out = (float*)d_out;

    float* ws = (float*)d_ws;
    float* e   = ws;                               // NEDGE*FE (67 MB)
    float* h0  = e + (size_t)NEDGE * FE;
    float* h1  = h0 + (size_t)NA * FN;
    float* Pi  = h1 + (size_t)NA * FN;             // NA*128*2 (f,c interleaved)
    float* Pj  = Pi + (size_t)NA * FN * 2;         // NA*128*2
    ushort_t* Whi  = (ushort_t*)(Pj + (size_t)NA * FN * 2);  // 12 * 384*128
    ushort_t* Wlo  = Whi + (size_t)12 * WTMAT;
    ushort_t* Wo1h = Wlo + (size_t)12 * WTMAT;               // 64*128
    ushort_t* Wo1l = Wo1h + (size_t)64 * 128;

    k_conv_w<<<36, 256, 0, stream>>>(Wnf, Wnc, Wef, Wec, Whi, Wlo);
    k_conv_wo<<<32, 256, 0, stream>>>(Wo1, Wo1h, Wo1l);
    k_init_h<<<(NA * FN) / 256, 256, 0, stream>>>(Z, emb, h0);

    float* hc = h0;
    float* hn = h1;
    for (int l = 0; l < 3; ++l) {
        const ushort_t* nf_h = Whi + (size_t)(l * 4 + 0) * WTMAT;
        const ushort_t* nf_l = Wlo + (size_t)(l * 4 + 0) * WTMAT;
        const ushort_t* nc_h = Whi + (size_t)(l * 4 + 1) * WTMAT;
        const ushort_t* nc_l = Wlo + (size_t)(l * 4 + 1) * WTMAT;
        const ushort_t* ef_h = Whi + (size_t)(l * 4 + 2) * WTMAT;
        const ushort_t* ef_l = Wlo + (size_t)(l * 4 + 2) * WTMAT;
        const ushort_t* ec_h = Whi + (size_t)(l * 4 + 3) * WTMAT;
        const ushort_t* ec_l = Wlo + (size_t)(l * 4 + 3) * WTMAT;

        // node stage
        k_proj<<<NA / 16, 512, 0, stream>>>(hc, nf_h, nf_l, nc_h, nc_l,
                                            bnf + l * FN, bnc + l * FN, Pi, Pj);
        if (l == 0)
            k_pass<1, 1, 0><<<NA, 256, 0, stream>>>(
                e, e, dist, nbr, Pi, Pj,
                nf_h + EPART, nf_l + EPART, nc_h + EPART, nc_l + EPART,
                hc, hn, nullptr, nullptr, nullptr, nullptr, nullptr, nullptr, nullptr);
        else
            k_pass<1, 0, 0><<<NA, 256, 0, stream>>>(
                e, e, dist, nbr, Pi, Pj,
                nf_h + EPART, nf_l + EPART, nc_h + EPART, nc_l + EPART,
                hc, hn, nullptr, nullptr, nullptr, nullptr, nullptr, nullptr, nullptr);

        // edge stage
        k_proj<<<NA / 16, 512, 0, stream>>>(hn, ef_h, ef_l, ec_h, ec_l,
                                            bef + l * FN, bec + l * FN, Pi, Pj);
        if (l < 2)
            k_pass<0, 0, 0><<<NA, 256, 0, stream>>>(
                e, e, dist, nbr, Pi, Pj,
                ef_h + EPART, ef_l + EPART, ec_h + EPART, ec_l + EPART,
                nullptr, nullptr, nullptr, nullptr, nullptr, nullptr, nullptr, nullptr, nullptr);
        else
            k_pass<0, 0, 1><<<NA, 256, 0, stream>>>(
                e, e, dist, nbr, Pi, Pj,
                ef_h + EPART, ef_l + EPART, ec_h + EPART, ec_l + EPART,
                nullptr, nullptr, Wo1h, Wo1l, bo1, Wo2, bo2, unit, out);

        float* t = hc; hc = hn; hn = t;
    }
}